// Round 1
// baseline (223.869 us; speedup 1.0000x reference)
//
#include <hip/hip_runtime.h>

#define NORD 256
#define TLEN 4096
#define NBATCH 512

// ---------------------------------------------------------------------------
// Kernel 1: column-wise inverse of lower-triangular part1 = I - 0.5*A.
// Block `col` (0..255) solves part1 * x = e_col  ->  P0[:,col] = 2*x - e_col = Ad[:,col]
// Block 256 solves part1 * x = Bm               ->  U0 = Bd = v_0
// Forward substitution: within each wave of 64 rows via __shfl (no barriers),
// cross-wave rank-64 updates via LDS (4 barriers total).
// ---------------------------------------------------------------------------
__global__ void inv_cols_kernel(const float* __restrict__ A,
                                const float* __restrict__ Bm,
                                float* __restrict__ P0,
                                float* __restrict__ U0) {
  const int col = blockIdx.x;
  const int i = threadIdx.x;          // global row
  const int wave = i >> 6;
  const int lane = i & 63;
  float b = (col < NORD) ? ((i == col) ? 1.0f : 0.0f) : Bm[i];
  const float invd = 1.0f / (1.0f - 0.5f * A[i * NORD + i]);  // L_ii = 1 - 0.5*A_ii
  __shared__ float xs[NORD];

  for (int w = 0; w < 4; ++w) {
    if (wave == w) {
      const int base = w << 6;
      for (int jj = 0; jj < 64; ++jj) {
        float bj = __shfl(b, jj);
        float dj = __shfl(invd, jj);
        float xj = bj * dj;           // x_j finalized by lane jj's running b
        if (lane > jj) {
          // L_ij = -0.5*A_ij  =>  b -= L_ij * x_j  ==  b += 0.5*A_ij*x_j
          b += 0.5f * A[i * NORD + base + jj] * xj;
        } else if (lane == jj) {
          b = xj;
        }
      }
      xs[i] = b;                      // publish this wave's solved x values
    }
    __syncthreads();
    if (wave > w) {
      const int base = w << 6;
      const float4* arow = reinterpret_cast<const float4*>(A + i * NORD + base);
#pragma unroll
      for (int q = 0; q < 16; ++q) {
        float4 a4 = arow[q];
        b += 0.5f * a4.x * xs[base + 4 * q + 0];
        b += 0.5f * a4.y * xs[base + 4 * q + 1];
        b += 0.5f * a4.z * xs[base + 4 * q + 2];
        b += 0.5f * a4.w * xs[base + 4 * q + 3];
      }
    }
  }
  // b = x_i
  if (col < NORD) {
    // Ad = 2*inv(part1) - I  (since part2 = 2I - part1)
    P0[i * NORD + col] = 2.0f * b - ((i == col) ? 1.0f : 0.0f);
  } else {
    U0[i] = b;                        // Bd = v_0
  }
}

// ---------------------------------------------------------------------------
// Kernel 2: one doubling stage.
//  z==0 (apply):  U_out[j][m] = sum_n P_in[m][n] * U_in[j][n],  j in [0,Jcount)
//                 (writes rows [Jcount, 2*Jcount) of U, passed as U_out)
//  z==1 (square): P_out = P_in * P_in
// 32x32 output tiles, 256 threads, 2x2 micro-tile, K-chunk 32.
// ---------------------------------------------------------------------------
__global__ void stage_kernel(const float* __restrict__ U_in,
                             float* __restrict__ U_out,
                             const float* __restrict__ P_in,
                             float* __restrict__ P_out,
                             int Jcount, int do_square) {
  const int t = threadIdx.x;
  const int tr = t >> 4, tc = t & 15;

  if (blockIdx.z == 1) {
    if (!do_square || blockIdx.x >= 8) return;
    __shared__ float At[32][33];
    __shared__ float Bt[32][33];
    const int m0 = blockIdx.x * 32, n0 = blockIdx.y * 32;
    float acc00 = 0.f, acc01 = 0.f, acc10 = 0.f, acc11 = 0.f;
    for (int k0 = 0; k0 < NORD; k0 += 32) {
      const int r = t >> 3, c4 = (t & 7) << 2;
      float4 va = *reinterpret_cast<const float4*>(&P_in[(m0 + r) * NORD + k0 + c4]);
      float4 vb = *reinterpret_cast<const float4*>(&P_in[(k0 + r) * NORD + n0 + c4]);
      At[r][c4] = va.x; At[r][c4 + 1] = va.y; At[r][c4 + 2] = va.z; At[r][c4 + 3] = va.w;
      Bt[r][c4] = vb.x; Bt[r][c4 + 1] = vb.y; Bt[r][c4 + 2] = vb.z; Bt[r][c4 + 3] = vb.w;
      __syncthreads();
#pragma unroll
      for (int k = 0; k < 32; ++k) {
        float a0 = At[tr][k], a1 = At[tr + 16][k];
        float b0 = Bt[k][tc], b1 = Bt[k][tc + 16];
        acc00 += a0 * b0; acc01 += a0 * b1;
        acc10 += a1 * b0; acc11 += a1 * b1;
      }
      __syncthreads();
    }
    P_out[(m0 + tr) * NORD + n0 + tc] = acc00;
    P_out[(m0 + tr) * NORD + n0 + tc + 16] = acc01;
    P_out[(m0 + tr + 16) * NORD + n0 + tc] = acc10;
    P_out[(m0 + tr + 16) * NORD + n0 + tc + 16] = acc11;
  } else {
    const int jb = blockIdx.x * 32;
    if (jb >= Jcount) return;
    __shared__ float Ut[32][33];
    __shared__ float Pt[32][33];
    const int m0 = blockIdx.y * 32;
    float acc00 = 0.f, acc01 = 0.f, acc10 = 0.f, acc11 = 0.f;
    for (int k0 = 0; k0 < NORD; k0 += 32) {
      const int r = t >> 3, c4 = (t & 7) << 2;
      const int j = jb + r;
      if (j < Jcount) {
        float4 vu = *reinterpret_cast<const float4*>(&U_in[j * NORD + k0 + c4]);
        Ut[r][c4] = vu.x; Ut[r][c4 + 1] = vu.y; Ut[r][c4 + 2] = vu.z; Ut[r][c4 + 3] = vu.w;
      } else {
        Ut[r][c4] = 0.f; Ut[r][c4 + 1] = 0.f; Ut[r][c4 + 2] = 0.f; Ut[r][c4 + 3] = 0.f;
      }
      float4 vp = *reinterpret_cast<const float4*>(&P_in[(m0 + r) * NORD + k0 + c4]);
      Pt[r][c4] = vp.x; Pt[r][c4 + 1] = vp.y; Pt[r][c4 + 2] = vp.z; Pt[r][c4 + 3] = vp.w;
      __syncthreads();
#pragma unroll
      for (int k = 0; k < 32; ++k) {
        float a0 = Ut[tr][k], a1 = Ut[tr + 16][k];
        float b0 = Pt[tc][k], b1 = Pt[tc + 16][k];
        acc00 += a0 * b0; acc01 += a0 * b1;
        acc10 += a1 * b0; acc11 += a1 * b1;
      }
      __syncthreads();
    }
    if (jb + tr < Jcount) {
      U_out[(jb + tr) * NORD + m0 + tc] = acc00;
      U_out[(jb + tr) * NORD + m0 + tc + 16] = acc01;
    }
    if (jb + tr + 16 < Jcount) {
      U_out[(jb + tr + 16) * NORD + m0 + tc] = acc10;
      U_out[(jb + tr + 16) * NORD + m0 + tc + 16] = acc11;
    }
  }
}

// ---------------------------------------------------------------------------
// Kernel 3: C[b][m] += sum_k f[b][k] * U[T-1-k][m]   (split-K over blockIdx.z)
// 64x64 tiles, 256 threads, 4x4 micro-tile, K-chunk 16, split-K = 8, atomicAdd.
// ---------------------------------------------------------------------------
__global__ void final_gemm(const float* __restrict__ f,
                           const float* __restrict__ U,
                           float* __restrict__ C) {
  const int b0 = blockIdx.x * 64;
  const int m0 = blockIdx.y * 64;
  const int k0base = blockIdx.z * 512;
  __shared__ float At[64][17];
  __shared__ float Bt[16][65];
  const int t = threadIdx.x;
  const int tr = t >> 4, tc = t & 15;
  float acc[4][4] = {};
  for (int kc = 0; kc < 512; kc += 16) {
    const int k0 = k0base + kc;
    {
      const int r = t >> 2, c4 = (t & 3) << 2;     // 64 rows x 16 cols
      float4 v = *reinterpret_cast<const float4*>(&f[(size_t)(b0 + r) * TLEN + k0 + c4]);
      At[r][c4] = v.x; At[r][c4 + 1] = v.y; At[r][c4 + 2] = v.z; At[r][c4 + 3] = v.w;
    }
    {
      const int r = t >> 4, c4 = (t & 15) << 2;    // 16 rows x 64 cols (reversed U rows)
      float4 v = *reinterpret_cast<const float4*>(&U[(size_t)(TLEN - 1 - (k0 + r)) * NORD + m0 + c4]);
      Bt[r][c4] = v.x; Bt[r][c4 + 1] = v.y; Bt[r][c4 + 2] = v.z; Bt[r][c4 + 3] = v.w;
    }
    __syncthreads();
#pragma unroll
    for (int k = 0; k < 16; ++k) {
      float a[4], bb[4];
#pragma unroll
      for (int ii = 0; ii < 4; ++ii) a[ii] = At[tr + 16 * ii][k];
#pragma unroll
      for (int jj = 0; jj < 4; ++jj) bb[jj] = Bt[k][tc + 16 * jj];
#pragma unroll
      for (int ii = 0; ii < 4; ++ii)
#pragma unroll
        for (int jj = 0; jj < 4; ++jj)
          acc[ii][jj] += a[ii] * bb[jj];
    }
    __syncthreads();
  }
#pragma unroll
  for (int ii = 0; ii < 4; ++ii)
#pragma unroll
    for (int jj = 0; jj < 4; ++jj)
      atomicAdd(&C[(size_t)(b0 + tr + 16 * ii) * NORD + m0 + tc + 16 * jj], acc[ii][jj]);
}

// ---------------------------------------------------------------------------
extern "C" void kernel_launch(void* const* d_in, const int* in_sizes, int n_in,
                              void* d_out, int out_size, void* d_ws, size_t ws_size,
                              hipStream_t stream) {
  const float* f  = (const float*)d_in[0];   // (512, 4096)
  const float* A  = (const float*)d_in[1];   // (256, 256) lower triangular
  const float* Bm = (const float*)d_in[2];   // (256, 1)
  // d_in[3] = init_state, exactly zero -> contributes nothing.

  float* ws = (float*)d_ws;
  float* Pa = ws;                         // 256*256
  float* Pb = ws + NORD * NORD;           // 256*256
  float* U  = ws + 2 * NORD * NORD;       // 4096*256 : U[j] = Ad^j * Bd

  hipMemsetAsync(d_out, 0, (size_t)NBATCH * NORD * sizeof(float), stream);

  hipLaunchKernelGGL(inv_cols_kernel, dim3(NORD + 1), dim3(NORD), 0, stream,
                     A, Bm, Pa, U);

  for (int s = 0; s < 12; ++s) {
    const int J = 1 << s;
    const float* Pin = (s & 1) ? Pb : Pa;
    float* Pout = (s & 1) ? Pa : Pb;
    const int do_sq = (s < 11) ? 1 : 0;
    int jx = (J + 31) / 32;
    if (jx < 8) jx = 8;
    dim3 grid(jx, 8, do_sq ? 2 : 1);
    hipLaunchKernelGGL(stage_kernel, grid, dim3(256), 0, stream,
                       U, U + (size_t)J * NORD, Pin, Pout, J, do_sq);
  }

  hipLaunchKernelGGL(final_gemm, dim3(8, 4, 8), dim3(256), 0, stream,
                     f, U, (float*)d_out);
}